// Round 3
// baseline (406.282 us; speedup 1.0000x reference)
//
#include <hip/hip_runtime.h>
#include <math.h>

// EdgeEmbedding: pos[2048,3] f32 -> (dist_edge[N,N,20], dir_edge[N,N,3], mask[N,N]) f32 flat in d_out.
// R2 lesson: bench dur_us includes a ~256 us harness poison fill; real kernel was ~130 us vs
// the 64 us write floor (fill kernel measured 6.28 TB/s on this buffer). 99.2% of output is
// zeros (edge density ~0.8%) -> zero via hipMemsetAsync (fill-rate path), then a sparse scan
// kernel writes only the ~34K active edges (~3.3 MB scattered).

#define NATOMS 2048
#define NBASIS 20
#define RCUT   5.0f

__global__ __launch_bounds__(256) void edge_scan_kernel(
    const float* __restrict__ pos, float* __restrict__ out)
{
    const int t = threadIdx.x;
    const int i = blockIdx.x >> 3;               // 8 blocks of 256 per row -> i block-uniform
    const int j = ((blockIdx.x & 7) << 8) | t;

    const float xi = pos[3 * i + 0], yi = pos[3 * i + 1], zi = pos[3 * i + 2];
    const float xj = pos[3 * j + 0], yj = pos[3 * j + 1], zj = pos[3 * j + 2];
    const float dx = xi - xj, dy = yi - yj, dz = zi - zj;
    float d2;
    {
        // match numpy's unfused mul-then-add rounding so the dist<r mask can't flip at the edge
#pragma clang fp contract(off)
        d2 = (dx * dx + dy * dy) + dz * dz;
    }
    const float dist = sqrtf(d2);
    if (!((dist < RCUT) && (i != j))) return;    // ~99.2% of lanes exit here

    // ---- active edge: ~34K of 4.19M pairs ----
    const float x  = dist * (1.0f / RCUT);
    const float x2 = x * x, x4 = x2 * x2, x8 = x4 * x4, x9 = x8 * x;
    // PolynomialCutoff p=9: 1 - 55 x^9 + 99 x^10 - 45 x^11
    const float env = 1.0f - 55.0f * x9 + 99.0f * x9 * x - 45.0f * x9 * x2;
    const float scale = env / x;

    // RadialBessel sin(k*pi*x), k=1..20 via Chebyshev recurrence
    const float theta = 3.14159265358979323846f * x;
    const float s1 = sinf(theta);
    const float twoc = 2.0f * cosf(theta);
    float vals[NBASIS];
    float pm2 = 0.0f, pm1 = s1;
    vals[0] = scale * s1;
#pragma unroll
    for (int k = 1; k < NBASIS; ++k) {
        const float sk = twoc * pm1 - pm2;
        vals[k] = scale * sk;
        pm2 = pm1; pm1 = sk;
    }

    const long long pair = (long long)i * NATOMS + j;
    float4* __restrict__ deq = (float4*)(out + pair * NBASIS);   // 80B stride -> 16B aligned
#pragma unroll
    for (int q = 0; q < 5; ++q)
        deq[q] = make_float4(vals[4 * q + 0], vals[4 * q + 1], vals[4 * q + 2], vals[4 * q + 3]);

    const float inv = 1.0f / dist;
    float* __restrict__ dir = out + (long long)NATOMS * NATOMS * NBASIS + pair * 3;
    dir[0] = dx * inv; dir[1] = dy * inv; dir[2] = dz * inv;
    out[(long long)NATOMS * NATOMS * (NBASIS + 3) + pair] = 1.0f;
}

extern "C" void kernel_launch(void* const* d_in, const int* in_sizes, int n_in,
                              void* d_out, int out_size, void* d_ws, size_t ws_size,
                              hipStream_t stream) {
    const float* pos = (const float*)d_in[0];
    float* out = (float*)d_out;
    // 1) zero all 402 MB at fill-kernel rate (~6.3 TB/s measured on this buffer) = ~64 us
    hipMemsetAsync(out, 0, (size_t)out_size * sizeof(float), stream);
    // 2) sparse scan: 2048*2048 pairs, one thread each; only ~0.8% write (~3.3 MB)
    edge_scan_kernel<<<dim3(NATOMS * 8), dim3(256), 0, stream>>>(pos, out);
}